// Round 4
// baseline (5076.234 us; speedup 1.0000x reference)
//
#include <hip/hip_runtime.h>

// Tensor-network binary tree, fp32 (precision: rel. error doubles per level,
// bf16 would blow the 2% threshold; no fp32 MFMA on CDNA4 -> VALU kernel).
//
// Round 4: kill the scalar-weight-path saturation seen in rounds 1-3
// (occupancy 44->79% left VALUBusy flat at ~37% => shared-resource limit:
// 8192 waves x ~20KB of per-wave s_load weight traffic = 162MB through the
// scalar path with lgkmcnt(0) drains). Restructure:
//   Kernel 1: block = 512 threads = 512 samples, ALL waves on the SAME
//     eighth-subtree e; its 19KB of w7..w3 staged once into LDS and read as
//     uniform-address ds_read (broadcast, conflict-free, precise waits).
//     Weight fetch drops 8x. x loads keep per-lane pattern + distance-2
//     register prefetch. Partials (8 f32 / sample-eighth) -> d_ws (16MB).
//   Kernel 2: fold 8 partials through w2/w1/w0 (LDS-staged), coalesced.

__device__ __forceinline__ void combine8(const float* __restrict__ w,
                                         const float L[8], const float R[8],
                                         float out[8]) {
    float acc[8];
#pragma unroll
    for (int k = 0; k < 8; ++k) acc[k] = 0.f;
#pragma unroll
    for (int i = 0; i < 8; ++i) {
#pragma unroll
        for (int j = 0; j < 8; ++j) {
            const float o = L[i] * R[j];
            const float* wp = w + (i * 8 + j) * 8;
#pragma unroll
            for (int k = 0; k < 8; ++k) acc[k] = fmaf(o, wp[k], acc[k]);
        }
    }
#pragma unroll
    for (int k = 0; k < 8; ++k) out[k] = acc[k];
}

__device__ __forceinline__ void copy8(float dst[8], const float src[8]) {
#pragma unroll
    for (int k = 0; k < 8; ++k) dst[k] = src[k];
}

// ---------------- kernel 1: per-eighth subtree, weights in LDS ------------
// LDS float layout: w7 slice @0 (256), w6 @256 (1024), w5 @1280 (2048),
//                   w4 @3328 (1024), w3 @4352 (512)  => 4864 floats = 19456B
__global__ __launch_bounds__(512, 6)
void tn_eighth_kernel(const float* __restrict__ x,
                      const float* __restrict__ w7,
                      const float* __restrict__ w6,
                      const float* __restrict__ w5,
                      const float* __restrict__ w4,
                      const float* __restrict__ w3,
                      float* __restrict__ ws) {
    __shared__ float lw[4864];
    const int tid = threadIdx.x;
    const int e = blockIdx.x >> 7;   // eighth index 0..7 (same for all waves)
    const int g = blockIdx.x & 127;  // sample group

    // cooperative, coalesced weight staging (float4 granularity)
    {
        float4* l4 = (float4*)lw;
        const float4* s7 = (const float4*)(w7 + (size_t)e * 256);
        const float4* s6 = (const float4*)(w6 + (size_t)e * 1024);
        const float4* s5 = (const float4*)(w5 + (size_t)e * 2048);
        const float4* s4 = (const float4*)(w4 + (size_t)e * 1024);
        const float4* s3 = (const float4*)(w3 + (size_t)e * 512);
        for (int i = tid; i < 64;  i += 512) l4[i]        = s7[i];
        for (int i = tid; i < 256; i += 512) l4[64 + i]   = s6[i];
        for (int i = tid; i < 512; i += 512) l4[320 + i]  = s5[i];
        for (int i = tid; i < 256; i += 512) l4[832 + i]  = s4[i];
        for (int i = tid; i < 128; i += 512) l4[1088 + i] = s3[i];
    }
    __syncthreads();

    const int s = g * 512 + tid;  // sample
    // x[b,f,p] flat = b*512 + f*2 + p; leaf n uses 4 floats at b*512+4n.
    // This thread's leaves: n = 16e + m  -> xp + 4m.
    const float* xp = x + (size_t)s * 512 + (size_t)e * 64;

    float p7[4], p6[8], p5[8], p4[8], res[8];

    float4 xa = *reinterpret_cast<const float4*>(xp);
    float4 xb = *reinterpret_cast<const float4*>(xp + 4);

#pragma unroll
    for (int m = 0; m < 16; ++m) {
        const float4 xv = xa;          // distance-2 register prefetch
        xa = xb;
        if (m < 14) xb = *reinterpret_cast<const float4*>(xp + (m + 2) * 4);

        // ---- leaf (w7): v4[k] = sum_{i,j<2} x0i x1j w7[n,i,j,k]
        float v4[4];
        {
            const float* w = lw + m * 16;
            const float o00 = xv.x * xv.z, o01 = xv.x * xv.w;
            const float o10 = xv.y * xv.z, o11 = xv.y * xv.w;
#pragma unroll
            for (int k = 0; k < 4; ++k)
                v4[k] = fmaf(o00, w[k],
                        fmaf(o01, w[4 + k],
                        fmaf(o10, w[8 + k], o11 * w[12 + k])));
        }
        if ((m & 1) == 0) {
#pragma unroll
            for (int k = 0; k < 4; ++k) p7[k] = v4[k];
            continue;
        }

        // ---- w6: 4x4 -> 8
        float v8[8];
        {
            const float* w = lw + 256 + (m >> 1) * 128;
#pragma unroll
            for (int k = 0; k < 8; ++k) v8[k] = 0.f;
#pragma unroll
            for (int i = 0; i < 4; ++i) {
#pragma unroll
                for (int j = 0; j < 4; ++j) {
                    const float o = p7[i] * v4[j];
                    const float* wp = w + (i * 4 + j) * 8;
#pragma unroll
                    for (int k = 0; k < 8; ++k) v8[k] = fmaf(o, wp[k], v8[k]);
                }
            }
        }
        if ((m & 2) == 0) { copy8(p6, v8); continue; }

        // ---- w5
        float t[8];
        combine8(lw + 1280 + (m >> 2) * 512, p6, v8, t);
        if ((m & 4) == 0) { copy8(p5, t); continue; }

        // ---- w4
        combine8(lw + 3328 + (m >> 3) * 512, p5, t, v8);
        if ((m & 8) == 0) { copy8(p4, v8); continue; }

        // ---- w3 (finishes this eighth; consumes w4's output v8)
        combine8(lw + 4352, p4, v8, res);
    }

    // partial result -> ws[e][s][0..8), coalesced float4 stores
    float4* o4 = reinterpret_cast<float4*>(ws + ((size_t)e * 65536 + (size_t)s) * 8);
    o4[0] = make_float4(res[0], res[1], res[2], res[3]);
    o4[1] = make_float4(res[4], res[5], res[6], res[7]);
}

// ---------------- kernel 2: fold 8 partials through w2/w1/w0 --------------
// LDS float layout: w2 @0 (2048), w1 @2048 (1024), w0 @3072 (128)
__global__ __launch_bounds__(256, 8)
void tn_combine_kernel(const float* __restrict__ ws,
                       const float* __restrict__ w2,
                       const float* __restrict__ w1,
                       const float* __restrict__ w0,
                       float* __restrict__ out) {
    __shared__ float lw[3200];
    const int tid = threadIdx.x;
    {
        float4* l4 = (float4*)lw;
        const float4* s2 = (const float4*)w2;
        const float4* s1 = (const float4*)w1;
        const float4* s0 = (const float4*)w0;
        for (int i = tid; i < 512; i += 256) l4[i]       = s2[i];
        for (int i = tid; i < 256; i += 256) l4[512 + i] = s1[i];
        for (int i = tid; i < 32;  i += 256) l4[768 + i] = s0[i];
    }
    __syncthreads();

    const int s = blockIdx.x * 256 + tid;

    float ra[8], rb[8], va[8], vb[8], v1a[8], v1b[8];
#define LOADP(ei, dst)                                                          \
    {                                                                           \
        const float4* p = reinterpret_cast<const float4*>(                      \
            ws + ((size_t)(ei) * 65536 + (size_t)s) * 8);                       \
        float4 u0 = p[0], u1 = p[1];                                            \
        dst[0] = u0.x; dst[1] = u0.y; dst[2] = u0.z; dst[3] = u0.w;             \
        dst[4] = u1.x; dst[5] = u1.y; dst[6] = u1.z; dst[7] = u1.w;             \
    }

    LOADP(0, ra); LOADP(1, rb); combine8(lw + 0,    ra, rb, va);
    LOADP(2, ra); LOADP(3, rb); combine8(lw + 512,  ra, rb, vb);
    combine8(lw + 2048, va, vb, v1a);
    LOADP(4, ra); LOADP(5, rb); combine8(lw + 1024, ra, rb, va);
    LOADP(6, ra); LOADP(7, rb); combine8(lw + 1536, ra, rb, vb);
    combine8(lw + 2048 + 512, va, vb, v1b);
#undef LOADP

    // root: out[l] = sum_ij v1a[i] v1b[j] w0[i,j,l]
    const float* r0 = lw + 3072;
    float o0 = 0.f, o1 = 0.f;
#pragma unroll
    for (int i = 0; i < 8; ++i) {
#pragma unroll
        for (int j = 0; j < 8; ++j) {
            const float o = v1a[i] * v1b[j];
            o0 = fmaf(o, r0[i * 16 + j * 2 + 0], o0);
            o1 = fmaf(o, r0[i * 16 + j * 2 + 1], o1);
        }
    }
    float2 r;
    r.x = o0;
    r.y = o1;
    *reinterpret_cast<float2*>(out + (size_t)s * 2) = r;
}

extern "C" void kernel_launch(void* const* d_in, const int* in_sizes, int n_in,
                              void* d_out, int out_size, void* d_ws, size_t ws_size,
                              hipStream_t stream) {
    const float* x  = (const float*)d_in[0];
    const float* w7 = (const float*)d_in[1];
    const float* w6 = (const float*)d_in[2];
    const float* w5 = (const float*)d_in[3];
    const float* w4 = (const float*)d_in[4];
    const float* w3 = (const float*)d_in[5];
    const float* w2 = (const float*)d_in[6];
    const float* w1 = (const float*)d_in[7];
    const float* w0 = (const float*)d_in[8];
    float* out = (float*)d_out;
    float* ws  = (float*)d_ws;  // needs 8 * 65536 * 8 * 4B = 16 MiB

    // kernel 1: 8 eighths x 128 sample-groups, 512 threads (1 sample each)
    hipLaunchKernelGGL(tn_eighth_kernel, dim3(1024), dim3(512), 0, stream,
                       x, w7, w6, w5, w4, w3, ws);
    // kernel 2: fold partials, 65536 threads
    hipLaunchKernelGGL(tn_combine_kernel, dim3(256), dim3(256), 0, stream,
                       ws, w2, w1, w0, out);
}

// Round 5
// 675.256 us; speedup vs baseline: 7.5175x; 7.5175x over previous
//
#include <hip/hip_runtime.h>

// Tensor-network binary tree, fp32 (precision: rel. error ~doubles per level
// over 8 levels; bf16/fp16 blow the 2% threshold; no fp32 MFMA -> VALU).
//
// Round 5. Round-4 post-mortem: 15.5 GB/dispatch of HBM traffic = register
// SPILL (LDS-weight ds_reads into VGPRs + full 16x unroll exploded pressure),
// plus per-wave redundant LDS broadcast of the whole weight stream is
// structurally bad (~1216 ds_read_b128 x 12cyc per wave on the shared LDS
// pipe). Revert to round-3's exact per-thread body (s_load weights via
// wave-uniform global pointers, #pragma unroll 2 -> VGPR=32, no blow-up).
// Keep round-4's GOOD idea: all 8 waves of a block work the SAME eighth e,
// and e = blockIdx&7 == XCD id under round-robin dispatch, so every block
// on an XCD marches through ONE shared 19.4KB scalar weight stream (sK$/L2
// resident) instead of 8 independent streams per block (round-3's ~37%
// VALUBusy scalar-latency wall). Partials go through d_ws (16MB); kernel 2
// (validated in round 4) folds them through w2/w1/w0.

__device__ __forceinline__ void combine8(const float* __restrict__ w,
                                         const float L[8], const float R[8],
                                         float out[8]) {
    float acc[8];
#pragma unroll
    for (int k = 0; k < 8; ++k) acc[k] = 0.f;
#pragma unroll
    for (int i = 0; i < 8; ++i) {
#pragma unroll
        for (int j = 0; j < 8; ++j) {
            const float o = L[i] * R[j];
            const float* wp = w + (i * 8 + j) * 8;
#pragma unroll
            for (int k = 0; k < 8; ++k) acc[k] = fmaf(o, wp[k], acc[k]);
        }
    }
#pragma unroll
    for (int k = 0; k < 8; ++k) out[k] = acc[k];
}

__device__ __forceinline__ void copy8(float dst[8], const float src[8]) {
#pragma unroll
    for (int k = 0; k < 8; ++k) dst[k] = src[k];
}

// ---------------- kernel 1: one eighth-subtree per block ------------------
__global__ __launch_bounds__(512, 8)
void tn_eighth_kernel(const float* __restrict__ x,
                      const float* __restrict__ w7,
                      const float* __restrict__ w6,
                      const float* __restrict__ w5,
                      const float* __restrict__ w4,
                      const float* __restrict__ w3,
                      float* __restrict__ ws) {
    const int tid = threadIdx.x;
    const int bid = blockIdx.x;
    const int e = bid & 7;   // eighth == XCD id (round-robin dispatch):
    const int g = bid >> 3;  // whole XCD shares ONE weight stream
    const int s = g * 512 + tid;  // sample

    // x[b,f,p] flat = b*512 + f*2 + p; leaf n uses 4 floats at b*512+4n.
    // This thread's leaves: n = 16e + m -> xp + 4m.
    const float* xp  = x  + (size_t)s * 512 + (size_t)e * 64;
    const float* pw7 = w7 + (size_t)e * 256;   // 16 nodes * 16 floats
    const float* pw6 = w6 + (size_t)e * 1024;  //  8 nodes * 128
    const float* pw5 = w5 + (size_t)e * 2048;  //  4 nodes * 512
    const float* pw4 = w4 + (size_t)e * 1024;  //  2 nodes * 512
    const float* pw3 = w3 + (size_t)e * 512;   //  1 node  * 512

    float p7[4], p6[8], p5[8], p4[8], res[8];

#pragma unroll 2
    for (int m = 0; m < 16; ++m) {
        // ---- leaf (w7): v4[k] = sum_{i,j<2} x0i x1j w7[n,i,j,k]
        const float4 xv = *reinterpret_cast<const float4*>(xp + m * 4);
        float v4[4];
        {
            const float* w = pw7 + m * 16;
            const float o00 = xv.x * xv.z, o01 = xv.x * xv.w;
            const float o10 = xv.y * xv.z, o11 = xv.y * xv.w;
#pragma unroll
            for (int k = 0; k < 4; ++k)
                v4[k] = fmaf(o00, w[k],
                        fmaf(o01, w[4 + k],
                        fmaf(o10, w[8 + k], o11 * w[12 + k])));
        }
        if ((m & 1) == 0) {
#pragma unroll
            for (int k = 0; k < 4; ++k) p7[k] = v4[k];
            continue;
        }

        // ---- w6: 4x4 -> 8
        float v8[8];
        {
            const float* w = pw6 + (m >> 1) * 128;
#pragma unroll
            for (int k = 0; k < 8; ++k) v8[k] = 0.f;
#pragma unroll
            for (int i = 0; i < 4; ++i) {
#pragma unroll
                for (int j = 0; j < 4; ++j) {
                    const float o = p7[i] * v4[j];
                    const float* wp = w + (i * 4 + j) * 8;
#pragma unroll
                    for (int k = 0; k < 8; ++k) v8[k] = fmaf(o, wp[k], v8[k]);
                }
            }
        }
        if ((m & 2) == 0) { copy8(p6, v8); continue; }

        // ---- w5
        float t[8];
        combine8(pw5 + (m >> 2) * 512, p6, v8, t);
        if ((m & 4) == 0) { copy8(p5, t); continue; }

        // ---- w4
        combine8(pw4 + (m >> 3) * 512, p5, t, v8);
        if ((m & 8) == 0) { copy8(p4, v8); continue; }

        // ---- w3 (finishes this eighth; consumes w4's output v8)
        combine8(pw3, p4, v8, res);
    }

    // partial -> ws[e][s][0..8), contiguous 32B per thread (fully coalesced)
    float4* o4 = reinterpret_cast<float4*>(ws + ((size_t)e * 65536 + (size_t)s) * 8);
    o4[0] = make_float4(res[0], res[1], res[2], res[3]);
    o4[1] = make_float4(res[4], res[5], res[6], res[7]);
}

// ---------------- kernel 2: fold 8 partials through w2/w1/w0 --------------
// LDS float layout: w2 @0 (2048), w1 @2048 (1024), w0 @3072 (128)
__global__ __launch_bounds__(256, 8)
void tn_combine_kernel(const float* __restrict__ ws,
                       const float* __restrict__ w2,
                       const float* __restrict__ w1,
                       const float* __restrict__ w0,
                       float* __restrict__ out) {
    __shared__ float lw[3200];
    const int tid = threadIdx.x;
    {
        float4* l4 = (float4*)lw;
        const float4* s2 = (const float4*)w2;
        const float4* s1 = (const float4*)w1;
        const float4* s0 = (const float4*)w0;
        for (int i = tid; i < 512; i += 256) l4[i]       = s2[i];
        for (int i = tid; i < 256; i += 256) l4[512 + i] = s1[i];
        for (int i = tid; i < 32;  i += 256) l4[768 + i] = s0[i];
    }
    __syncthreads();

    const int s = blockIdx.x * 256 + tid;

    float ra[8], rb[8], va[8], vb[8], v1a[8], v1b[8];
#define LOADP(ei, dst)                                                          \
    {                                                                           \
        const float4* p = reinterpret_cast<const float4*>(                      \
            ws + ((size_t)(ei) * 65536 + (size_t)s) * 8);                       \
        float4 u0 = p[0], u1 = p[1];                                            \
        dst[0] = u0.x; dst[1] = u0.y; dst[2] = u0.z; dst[3] = u0.w;             \
        dst[4] = u1.x; dst[5] = u1.y; dst[6] = u1.z; dst[7] = u1.w;             \
    }

    LOADP(0, ra); LOADP(1, rb); combine8(lw + 0,    ra, rb, va);
    LOADP(2, ra); LOADP(3, rb); combine8(lw + 512,  ra, rb, vb);
    combine8(lw + 2048, va, vb, v1a);
    LOADP(4, ra); LOADP(5, rb); combine8(lw + 1024, ra, rb, va);
    LOADP(6, ra); LOADP(7, rb); combine8(lw + 1536, ra, rb, vb);
    combine8(lw + 2048 + 512, va, vb, v1b);
#undef LOADP

    // root: out[l] = sum_ij v1a[i] v1b[j] w0[i,j,l]
    const float* r0 = lw + 3072;
    float o0 = 0.f, o1 = 0.f;
#pragma unroll
    for (int i = 0; i < 8; ++i) {
#pragma unroll
        for (int j = 0; j < 8; ++j) {
            const float o = v1a[i] * v1b[j];
            o0 = fmaf(o, r0[i * 16 + j * 2 + 0], o0);
            o1 = fmaf(o, r0[i * 16 + j * 2 + 1], o1);
        }
    }
    float2 r;
    r.x = o0;
    r.y = o1;
    *reinterpret_cast<float2*>(out + (size_t)s * 2) = r;
}

extern "C" void kernel_launch(void* const* d_in, const int* in_sizes, int n_in,
                              void* d_out, int out_size, void* d_ws, size_t ws_size,
                              hipStream_t stream) {
    const float* x  = (const float*)d_in[0];
    const float* w7 = (const float*)d_in[1];
    const float* w6 = (const float*)d_in[2];
    const float* w5 = (const float*)d_in[3];
    const float* w4 = (const float*)d_in[4];
    const float* w3 = (const float*)d_in[5];
    const float* w2 = (const float*)d_in[6];
    const float* w1 = (const float*)d_in[7];
    const float* w0 = (const float*)d_in[8];
    float* out = (float*)d_out;
    float* ws  = (float*)d_ws;  // 8 * 65536 * 8 * 4B = 16 MiB

    // kernel 1: e = blockIdx&7 (== XCD), g = blockIdx>>3; 512 samples/block
    hipLaunchKernelGGL(tn_eighth_kernel, dim3(1024), dim3(512), 0, stream,
                       x, w7, w6, w5, w4, w3, ws);
    // kernel 2: fold partials, 65536 threads
    hipLaunchKernelGGL(tn_combine_kernel, dim3(256), dim3(256), 0, stream,
                       ws, w2, w1, w0, out);
}